// Round 5
// baseline (64.413 us; speedup 1.0000x reference)
//
#include <hip/hip_runtime.h>

#define S_LEN 2048
#define B_DIM 32
#define H_DIM 1024
#define ROWS 16      // s-rows per wave in energy kernel
#define KSPLIT 8     // k-split partials in proj
#define KCH (H_DIM / KSPLIT)  // 128
#define BGRP 8       // b's per proj block (W-redundancy = B/BGRP = 4x)

typedef float fx4 __attribute__((ext_vector_type(4)));

// ---------------------------------------------------------------------------
// Kernel 1: vp[kp,b,h] = sum_{k in chunk kp} dec[b,k] * W[k,h]
// Grid: (H/256, B/BGRP, KSPLIT) = (4, 4, 8) = 128 blocks x 256 threads.
// Each W element is loaded by only B/BGRP = 4 blocks (16 MB total L2/L3 flow
// vs 128 MB when one block per b) -- one coalesced W load feeds 8 FMAs.
// dec loads thread-uniform -> s_load. 128 W loads/thread; 128 blocks give
// ~4 MB of loads in flight to cover the cold-HBM W fetch (W is evicted from
// L3 every replay by the 256 MiB enc stream).
// ---------------------------------------------------------------------------
__global__ __launch_bounds__(256) void proj_kernel(
    const float* __restrict__ dec, const float* __restrict__ W,
    float* __restrict__ vp)
{
    const int h  = blockIdx.x * 256 + threadIdx.x;
    const int b0 = blockIdx.y * BGRP;
    const int kp = blockIdx.z;
    const int k0 = kp * KCH;

    float acc[BGRP];
#pragma unroll
    for (int j = 0; j < BGRP; ++j) acc[j] = 0.f;

    for (int kk = 0; kk < KCH; ++kk) {
        const int k = k0 + kk;
        const float w = W[(size_t)k * H_DIM + h];
#pragma unroll
        for (int j = 0; j < BGRP; ++j)
            acc[j] += dec[(size_t)(b0 + j) * H_DIM + k] * w;  // uniform -> s_load
    }

#pragma unroll
    for (int j = 0; j < BGRP; ++j)
        vp[((size_t)kp * B_DIM + b0 + j) * H_DIM + h] = acc[j];
}

// ---------------------------------------------------------------------------
// Kernel 2: v[b,h] = sum_kp vp[kp,b,h].  32 blocks x 256 threads, one fx4
// per thread, 8 fx4 loads (all L2-resident). ~1 us, dispatch-dominated.
// ---------------------------------------------------------------------------
__global__ __launch_bounds__(256) void vsum_kernel(
    const float* __restrict__ vp, float* __restrict__ v)
{
    const int b = blockIdx.x;
    const int t = threadIdx.x;                 // one fx4 (4 h's) per thread
    fx4 s = {0.f, 0.f, 0.f, 0.f};
#pragma unroll
    for (int kp = 0; kp < KSPLIT; ++kp) {
        const fx4* __restrict__ p = reinterpret_cast<const fx4*>(
            vp + ((size_t)kp * B_DIM + b) * H_DIM);
        s += p[t];
    }
    reinterpret_cast<fx4*>(v + (size_t)b * H_DIM)[t] = s;
}

// ---------------------------------------------------------------------------
// Kernel 3: e[b,s] = dot(enc[s,b,:], v[b,:])
// Grid: (B/4, S/ROWS) = (8, 128) = 1024 blocks -- exactly 4 blocks/CU, one
// occupancy generation, zero block churn. Wave wv owns b = 4x+wv and 16
// consecutive s (64 KB of enc). v row in 16 VGPRs, loaded once (4 loads).
// 4 groups x [4 rows x 4 chunks]: 16 plain float4 loads in flight per group
// (m13's 6.29 TB/s recipe), 16 interleaved reduce chains, 4 fx4 stores.
// ---------------------------------------------------------------------------
__global__ __launch_bounds__(256) void energy_kernel(
    const float* __restrict__ enc, const float* __restrict__ v,
    float* __restrict__ e)
{
    const int lane = threadIdx.x & 63;
    const int wv   = threadIdx.x >> 6;
    const int b    = blockIdx.x * 4 + wv;
    const int s0   = blockIdx.y * ROWS;

    const fx4* __restrict__ vrow =
        reinterpret_cast<const fx4*>(v + (size_t)b * H_DIM);
    fx4 vf[4];
#pragma unroll
    for (int i = 0; i < 4; ++i) vf[i] = vrow[lane + 64 * i];

    float acc[ROWS];
    for (int g = 0; g < 4; ++g) {
        fx4 a[4][4];
#pragma unroll
        for (int r = 0; r < 4; ++r) {
            const fx4* __restrict__ ep = reinterpret_cast<const fx4*>(
                enc + ((size_t)(s0 + g * 4 + r) * B_DIM + b) * H_DIM);
#pragma unroll
            for (int i = 0; i < 4; ++i)
                a[r][i] = ep[lane + 64 * i];
        }
#pragma unroll
        for (int r = 0; r < 4; ++r) {
            float t = 0.f;
#pragma unroll
            for (int i = 0; i < 4; ++i)
                t += a[r][i].x * vf[i].x + a[r][i].y * vf[i].y +
                     a[r][i].z * vf[i].z + a[r][i].w * vf[i].w;
            acc[g * 4 + r] = t;
        }
    }

#pragma unroll
    for (int off = 32; off; off >>= 1) {
#pragma unroll
        for (int r = 0; r < ROWS; ++r)
            acc[r] += __shfl_xor(acc[r], off, 64);
    }

    if (lane == 0) {
        fx4* ep = reinterpret_cast<fx4*>(e + (size_t)b * S_LEN + s0);
#pragma unroll
        for (int q = 0; q < 4; ++q) {
            fx4 o;
            o.x = acc[4 * q + 0]; o.y = acc[4 * q + 1];
            o.z = acc[4 * q + 2]; o.w = acc[4 * q + 3];
            ep[q] = o;
        }
    }
}

// ---------------------------------------------------------------------------
// Kernel 4: out[b,0,s] = softmax_s(e[b,s]).  One block per b (32 blocks).
// Bias term c[b] omitted: constant per row, softmax-invariant.
// ---------------------------------------------------------------------------
__global__ __launch_bounds__(256) void softmax_kernel(
    const float* __restrict__ e, float* __restrict__ out)
{
    __shared__ float red[4];
    const int b    = blockIdx.x;
    const int tid  = threadIdx.x;
    const int lane = tid & 63;
    const int wv   = tid >> 6;
    const float* __restrict__ row = e + (size_t)b * S_LEN;

    float vals[8];
    float m = -1e30f;
#pragma unroll
    for (int i = 0; i < 8; ++i) {
        vals[i] = row[tid + 256 * i];
        m = fmaxf(m, vals[i]);
    }
#pragma unroll
    for (int off = 32; off; off >>= 1)
        m = fmaxf(m, __shfl_xor(m, off, 64));
    if (lane == 0) red[wv] = m;
    __syncthreads();
    m = fmaxf(fmaxf(red[0], red[1]), fmaxf(red[2], red[3]));

    float sum = 0.0f;
#pragma unroll
    for (int i = 0; i < 8; ++i) {
        vals[i] = __expf(vals[i] - m);
        sum += vals[i];
    }
#pragma unroll
    for (int off = 32; off; off >>= 1)
        sum += __shfl_xor(sum, off, 64);
    __syncthreads();                 // red reuse hazard
    if (lane == 0) red[wv] = sum;
    __syncthreads();
    sum = red[0] + red[1] + red[2] + red[3];

    const float inv = 1.0f / sum;
#pragma unroll
    for (int i = 0; i < 8; ++i)
        out[(size_t)b * S_LEN + tid + 256 * i] = vals[i] * inv;
}

// ---------------------------------------------------------------------------
extern "C" void kernel_launch(void* const* d_in, const int* in_sizes, int n_in,
                              void* d_out, int out_size, void* d_ws, size_t ws_size,
                              hipStream_t stream)
{
    const float* dec = (const float*)d_in[0];   // [B,H]
    const float* enc = (const float*)d_in[1];   // [S,B,H]
    const float* W   = (const float*)d_in[2];   // [H,H]
    // d_in[3] = bias: constant-per-row contribution, softmax-invariant -> unused
    float* out = (float*)d_out;                 // [B,1,S] flat

    float* vp = (float*)d_ws;                   // KSPLIT*B*H floats (1 MiB)
    float* v  = vp + KSPLIT * B_DIM * H_DIM;    // B*H floats (128 KiB)
    float* e  = v + B_DIM * H_DIM;              // B*S floats (256 KiB)

    proj_kernel<<<dim3(H_DIM / 256, B_DIM / BGRP, KSPLIT), 256, 0, stream>>>(dec, W, vp);
    vsum_kernel<<<B_DIM, 256, 0, stream>>>(vp, v);
    energy_kernel<<<dim3(B_DIM / 4, S_LEN / ROWS), 256, 0, stream>>>(enc, v, e);
    softmax_kernel<<<B_DIM, 256, 0, stream>>>(e, out);
}

// Round 6
// 60.842 us; speedup vs baseline: 1.0587x; 1.0587x over previous
//
#include <hip/hip_runtime.h>

#define S_LEN 2048
#define B_DIM 32
#define H_DIM 1024
#define ROWS 8       // s-rows per wave in energy kernel (round-4 optimum)
#define KSPLIT 8     // k-split partials in proj
#define KCH (H_DIM / KSPLIT)  // 128
#define BGRP 4       // b's per proj block (W redundancy = B/BGRP = 8x)

typedef float fx4 __attribute__((ext_vector_type(4)));

// ---------------------------------------------------------------------------
// Kernel 1: vp[kp,b,h] = sum_{k in chunk kp} dec[b,k] * W[k,h]
// Grid: (H/256, B/BGRP, KSPLIT) = (4, 8, 8) = 256 blocks x 256 threads --
// exactly 1 block/CU, all CUs active on the cold-HBM W fetch (W is evicted
// from L3 every replay by the 256 MiB enc stream). One coalesced W load
// feeds 4 FMAs; W redundancy 8x -> 32 MB L2/L3 flow (vs 128 MB in round 4).
// dec loads thread-uniform -> s_load. 128 W loads/thread, unroll-4 for ILP.
// ---------------------------------------------------------------------------
__global__ __launch_bounds__(256) void proj_kernel(
    const float* __restrict__ dec, const float* __restrict__ W,
    float* __restrict__ vp)
{
    const int h  = blockIdx.x * 256 + threadIdx.x;
    const int b0 = blockIdx.y * BGRP;
    const int k0 = blockIdx.z * KCH;

    float acc[BGRP];
#pragma unroll
    for (int j = 0; j < BGRP; ++j) acc[j] = 0.f;

#pragma unroll 4
    for (int kk = 0; kk < KCH; ++kk) {
        const int k = k0 + kk;
        const float w = W[(size_t)k * H_DIM + h];
#pragma unroll
        for (int j = 0; j < BGRP; ++j)
            acc[j] += dec[(size_t)(b0 + j) * H_DIM + k] * w;  // uniform -> s_load
    }

#pragma unroll
    for (int j = 0; j < BGRP; ++j)
        vp[((size_t)blockIdx.z * B_DIM + b0 + j) * H_DIM + h] = acc[j];
}

// ---------------------------------------------------------------------------
// Kernel 2: e[b,s] = dot(enc[s,b,:], v[b,:]),  v = sum of 8 partials.
// Round-4 structure exactly: grid (B/4, S/ROWS) = (8, 256), x fastest ->
// 8 consecutive blocks cover one full 8-row x 128 KB slab (1 MB)
// sequentially. Wave wv owns b = 4x+wv and 8 consecutive s. v row summed
// once into 16 VGPRs (32 L2-resident loads); enc via plain float4 loads
// (m13's 6.29 TB/s recipe), 16 loads in flight per half-group, two
// half-groups to bound VGPR pressure, 8 interleaved reduce chains.
// ---------------------------------------------------------------------------
__global__ __launch_bounds__(256) void energy_kernel(
    const float* __restrict__ enc, const float* __restrict__ vp,
    float* __restrict__ e)
{
    const int lane = threadIdx.x & 63;
    const int wv   = threadIdx.x >> 6;
    const int b    = blockIdx.x * 4 + wv;
    const int s0   = blockIdx.y * ROWS;

    fx4 vf[4];
#pragma unroll
    for (int i = 0; i < 4; ++i) {
        fx4 t = {0.f, 0.f, 0.f, 0.f};
#pragma unroll
        for (int kp = 0; kp < KSPLIT; ++kp) {
            const fx4* __restrict__ p = reinterpret_cast<const fx4*>(
                vp + ((size_t)kp * B_DIM + b) * H_DIM);
            t += p[lane + 64 * i];
        }
        vf[i] = t;
    }

    float acc[ROWS];
    for (int g = 0; g < 2; ++g) {
        fx4 a[4][4];
#pragma unroll
        for (int r = 0; r < 4; ++r) {
            const fx4* __restrict__ ep = reinterpret_cast<const fx4*>(
                enc + ((size_t)(s0 + g * 4 + r) * B_DIM + b) * H_DIM);
#pragma unroll
            for (int i = 0; i < 4; ++i)
                a[r][i] = ep[lane + 64 * i];
        }
#pragma unroll
        for (int r = 0; r < 4; ++r) {
            float t = 0.f;
#pragma unroll
            for (int i = 0; i < 4; ++i)
                t += a[r][i].x * vf[i].x + a[r][i].y * vf[i].y +
                     a[r][i].z * vf[i].z + a[r][i].w * vf[i].w;
            acc[g * 4 + r] = t;
        }
    }

#pragma unroll
    for (int off = 32; off; off >>= 1) {
#pragma unroll
        for (int r = 0; r < ROWS; ++r)
            acc[r] += __shfl_xor(acc[r], off, 64);
    }

    if (lane == 0) {
        fx4 o0, o1;
        o0.x = acc[0]; o0.y = acc[1]; o0.z = acc[2]; o0.w = acc[3];
        o1.x = acc[4]; o1.y = acc[5]; o1.z = acc[6]; o1.w = acc[7];
        fx4* ep = reinterpret_cast<fx4*>(e + (size_t)b * S_LEN + s0);
        ep[0] = o0;
        ep[1] = o1;
    }
}

// ---------------------------------------------------------------------------
// Kernel 3: out[b,0,s] = softmax_s(e[b,s]).  One block per b (32 blocks).
// Bias term c[b] omitted: constant per row, softmax-invariant.
// ---------------------------------------------------------------------------
__global__ __launch_bounds__(256) void softmax_kernel(
    const float* __restrict__ e, float* __restrict__ out)
{
    __shared__ float red[4];
    const int b    = blockIdx.x;
    const int tid  = threadIdx.x;
    const int lane = tid & 63;
    const int wv   = tid >> 6;
    const float* __restrict__ row = e + (size_t)b * S_LEN;

    float vals[8];
    float m = -1e30f;
#pragma unroll
    for (int i = 0; i < 8; ++i) {
        vals[i] = row[tid + 256 * i];
        m = fmaxf(m, vals[i]);
    }
#pragma unroll
    for (int off = 32; off; off >>= 1)
        m = fmaxf(m, __shfl_xor(m, off, 64));
    if (lane == 0) red[wv] = m;
    __syncthreads();
    m = fmaxf(fmaxf(red[0], red[1]), fmaxf(red[2], red[3]));

    float sum = 0.0f;
#pragma unroll
    for (int i = 0; i < 8; ++i) {
        vals[i] = __expf(vals[i] - m);
        sum += vals[i];
    }
#pragma unroll
    for (int off = 32; off; off >>= 1)
        sum += __shfl_xor(sum, off, 64);
    __syncthreads();                 // red reuse hazard
    if (lane == 0) red[wv] = sum;
    __syncthreads();
    sum = red[0] + red[1] + red[2] + red[3];

    const float inv = 1.0f / sum;
#pragma unroll
    for (int i = 0; i < 8; ++i)
        out[(size_t)b * S_LEN + tid + 256 * i] = vals[i] * inv;
}

// ---------------------------------------------------------------------------
extern "C" void kernel_launch(void* const* d_in, const int* in_sizes, int n_in,
                              void* d_out, int out_size, void* d_ws, size_t ws_size,
                              hipStream_t stream)
{
    const float* dec = (const float*)d_in[0];   // [B,H]
    const float* enc = (const float*)d_in[1];   // [S,B,H]
    const float* W   = (const float*)d_in[2];   // [H,H]
    // d_in[3] = bias: constant-per-row contribution, softmax-invariant -> unused
    float* out = (float*)d_out;                 // [B,1,S] flat

    float* vp = (float*)d_ws;                   // KSPLIT*B*H floats (1 MiB)
    float* e  = vp + KSPLIT * B_DIM * H_DIM;    // B*S floats (256 KiB)

    proj_kernel<<<dim3(H_DIM / 256, B_DIM / BGRP, KSPLIT), 256, 0, stream>>>(dec, W, vp);
    energy_kernel<<<dim3(B_DIM / 4, S_LEN / ROWS), 256, 0, stream>>>(enc, vp, e);
    softmax_kernel<<<B_DIM, 256, 0, stream>>>(e, out);
}